// Round 1
// 572.908 us; speedup vs baseline: 1.5749x; 1.5749x over previous
//
#include <hip/hip_runtime.h>
#include <hip/hip_bf16.h>
#include <math.h>

// Problem constants
#define BB 8
#define LLEN 1024
#define DDIM 512
#define HH 8
#define DLAT 512
#define NROW (BB * LLEN)        // 8192
#define ROWELEM 4194304         // 8192*512

typedef __bf16 bf16x8 __attribute__((ext_vector_type(8)));
typedef __bf16 bf16x4 __attribute__((ext_vector_type(4)));
typedef float  f32x4  __attribute__((ext_vector_type(4)));

__device__ inline __bf16 f2bf(float f) {
    union { float f; unsigned u; } a; a.f = f;
    unsigned r = (a.u + 0x7fffu + ((a.u >> 16) & 1u)) >> 16;
    union { unsigned short s; __bf16 b; } o; o.s = (unsigned short)r;
    return o.b;
}

// ---------------------------------------------------------------------------
// Weight transpose + cast: W[K][N] fp32 -> WT[N][K] bf16   (K=N=512)
// ---------------------------------------------------------------------------
__global__ __launch_bounds__(256) void wtrans_kernel(
    const float* __restrict__ W, __bf16* __restrict__ WT)
{
    __shared__ float t[64][65];
    const int tid = threadIdx.x;
    const int bx = blockIdx.x & 7;        // col tile (N)
    const int by = blockIdx.x >> 3;       // row tile (K)
    const int r0 = by * 64, c0 = bx * 64;

    #pragma unroll
    for (int p = 0; p < 4; ++p) {
        int r = p * 16 + (tid >> 4);
        int c = (tid & 15) * 4;
        f32x4 v = *(const f32x4*)(W + (size_t)(r0 + r) * 512 + c0 + c);
        t[r][c] = v[0]; t[r][c + 1] = v[1]; t[r][c + 2] = v[2]; t[r][c + 3] = v[3];
    }
    __syncthreads();
    #pragma unroll
    for (int p = 0; p < 4; ++p) {
        int c = p * 16 + (tid >> 4);      // output row (original col)
        int rc = (tid & 15) * 4;          // original row chunk
        bf16x4 o;
        #pragma unroll
        for (int m = 0; m < 4; ++m) o[m] = f2bf(t[rc + m][c]);
        *(bf16x4*)(WT + (size_t)(c0 + c) * 512 + r0 + rc) = o;
    }
}

// hi/lo split variant for near-fp32 split GEMMs
__global__ __launch_bounds__(256) void wtrans_hilo_kernel(
    const float* __restrict__ W, __bf16* __restrict__ WTh, __bf16* __restrict__ WTl)
{
    __shared__ float t[64][65];
    const int tid = threadIdx.x;
    const int bx = blockIdx.x & 7;
    const int by = blockIdx.x >> 3;
    const int r0 = by * 64, c0 = bx * 64;

    #pragma unroll
    for (int p = 0; p < 4; ++p) {
        int r = p * 16 + (tid >> 4);
        int c = (tid & 15) * 4;
        f32x4 v = *(const f32x4*)(W + (size_t)(r0 + r) * 512 + c0 + c);
        t[r][c] = v[0]; t[r][c + 1] = v[1]; t[r][c + 2] = v[2]; t[r][c + 3] = v[3];
    }
    __syncthreads();
    #pragma unroll
    for (int p = 0; p < 4; ++p) {
        int c = p * 16 + (tid >> 4);
        int rc = (tid & 15) * 4;
        bf16x4 oh, ol;
        #pragma unroll
        for (int m = 0; m < 4; ++m) {
            float v = t[rc + m][c];
            __bf16 hi = f2bf(v);
            oh[m] = hi;
            ol[m] = f2bf(v - (float)hi);
        }
        *(bf16x4*)(WTh + (size_t)(c0 + c) * 512 + r0 + rc) = oh;
        *(bf16x4*)(WTl + (size_t)(c0 + c) * 512 + r0 + rc) = ol;
    }
}

// ---------------------------------------------------------------------------
// MFMA GEMM (QKV): C_bf16[M,512] = bf16(A_f32[M,512]) @ Bt[512,512]^T + bias
// BM=128 BN=64 BK=64; 256 thr = 4 waves (2m x 2n); wave tile 64x32.
// Fragment mapping identical to the verified attn MFMAs:
//   A op: lane m=lid, k=quad*8+j ; B op: lane n=lid, k=quad*8+j
//   C: col=lid (n), row=quad*4+reg (m)
// ---------------------------------------------------------------------------
__global__ __launch_bounds__(256) void gemm_qkv_mfma(
    const float* __restrict__ A, const __bf16* __restrict__ Bt,
    const float* __restrict__ bias, __bf16* __restrict__ C)
{
    const int tid  = threadIdx.x;
    const int w    = tid >> 6, lane = tid & 63;
    const int quad = lane >> 4, lid = lane & 15;
    const int wm = w >> 1, wn = w & 1;
    const int col0 = blockIdx.x * 64;
    const int row0 = blockIdx.y * 128;

    __shared__ __bf16 As[128][72];   // pad 8: row stride 144B -> uniform banks
    __shared__ __bf16 Bs[64][72];

    const f32x4 zero = {0.f, 0.f, 0.f, 0.f};
    f32x4 acc[4][2];
    #pragma unroll
    for (int i = 0; i < 4; ++i)
        #pragma unroll
        for (int j = 0; j < 2; ++j) acc[i][j] = zero;

    for (int kt = 0; kt < 512; kt += 64) {
        __syncthreads();
        // stage A (fp32 -> bf16): wave covers 32 rows; 8 passes x 4 rows
        {
            const int rr = lane >> 4;        // 0..3
            const int cc = lane & 15;        // f32x4 chunk
            #pragma unroll
            for (int p = 0; p < 8; ++p) {
                int r = w * 32 + p * 4 + rr;
                f32x4 v = *(const f32x4*)(A + (size_t)(row0 + r) * 512 + kt + cc * 4);
                bf16x4 o;
                #pragma unroll
                for (int m = 0; m < 4; ++m) o[m] = f2bf(v[m]);
                *(bf16x4*)&As[r][cc * 4] = o;
            }
        }
        // stage B (bf16 copy): wave covers 16 rows; 2 passes x 8 rows
        {
            const int rr = lane >> 3;        // 0..7
            const int cc = lane & 7;         // 16B chunk
            #pragma unroll
            for (int p = 0; p < 2; ++p) {
                int r = w * 16 + p * 8 + rr;
                *(bf16x8*)&Bs[r][cc * 8] =
                    *(const bf16x8*)(Bt + (size_t)(col0 + r) * 512 + kt + cc * 8);
            }
        }
        __syncthreads();
        #pragma unroll
        for (int ks = 0; ks < 2; ++ks) {
            bf16x8 a[4], b[2];
            #pragma unroll
            for (int i = 0; i < 4; ++i)
                a[i] = *(const bf16x8*)&As[wm * 64 + i * 16 + lid][ks * 32 + quad * 8];
            #pragma unroll
            for (int j = 0; j < 2; ++j)
                b[j] = *(const bf16x8*)&Bs[wn * 32 + j * 16 + lid][ks * 32 + quad * 8];
            #pragma unroll
            for (int i = 0; i < 4; ++i)
                #pragma unroll
                for (int j = 0; j < 2; ++j)
                    acc[i][j] = __builtin_amdgcn_mfma_f32_16x16x32_bf16(a[i], b[j], acc[i][j], 0, 0, 0);
        }
    }

    float bcol[2];
    #pragma unroll
    for (int j = 0; j < 2; ++j) bcol[j] = bias[col0 + wn * 32 + j * 16 + lid];
    #pragma unroll
    for (int i = 0; i < 4; ++i)
        #pragma unroll
        for (int j = 0; j < 2; ++j) {
            int colg = col0 + wn * 32 + j * 16 + lid;
            #pragma unroll
            for (int r = 0; r < 4; ++r) {
                int rowg = row0 + wm * 64 + i * 16 + quad * 4 + r;
                C[(size_t)rowg * 512 + colg] = f2bf(acc[i][j][r] + bcol[j]);
            }
        }
}

// ---------------------------------------------------------------------------
// Split-bf16 3-pass MFMA GEMM (near-fp32):
// C_f32 = (Ahi+Alo) @ (Bthi+Btlo)^T + bias,  dropping only lo*lo (~2^-18)
// ---------------------------------------------------------------------------
__global__ __launch_bounds__(256) void gemm_split_mfma(
    const __bf16* __restrict__ Ahi, const __bf16* __restrict__ Alo,
    const __bf16* __restrict__ Bth, const __bf16* __restrict__ Btl,
    const float* __restrict__ bias, float* __restrict__ C)
{
    const int tid  = threadIdx.x;
    const int w    = tid >> 6, lane = tid & 63;
    const int quad = lane >> 4, lid = lane & 15;
    const int wm = w >> 1, wn = w & 1;
    const int col0 = blockIdx.x * 64;
    const int row0 = blockIdx.y * 128;

    __shared__ __bf16 Ah[128][72];
    __shared__ __bf16 Al[128][72];
    __shared__ __bf16 Bh[64][72];
    __shared__ __bf16 Bl[64][72];

    const f32x4 zero = {0.f, 0.f, 0.f, 0.f};
    f32x4 acc[4][2];
    #pragma unroll
    for (int i = 0; i < 4; ++i)
        #pragma unroll
        for (int j = 0; j < 2; ++j) acc[i][j] = zero;

    const int rr = lane >> 3, cc = lane & 7;

    for (int kt = 0; kt < 512; kt += 64) {
        __syncthreads();
        #pragma unroll
        for (int p = 0; p < 4; ++p) {       // A: 32 rows per wave, 8 rows/pass
            int r = w * 32 + p * 8 + rr;
            size_t g = (size_t)(row0 + r) * 512 + kt + cc * 8;
            *(bf16x8*)&Ah[r][cc * 8] = *(const bf16x8*)(Ahi + g);
            *(bf16x8*)&Al[r][cc * 8] = *(const bf16x8*)(Alo + g);
        }
        #pragma unroll
        for (int p = 0; p < 2; ++p) {       // B: 16 rows per wave
            int r = w * 16 + p * 8 + rr;
            size_t g = (size_t)(col0 + r) * 512 + kt + cc * 8;
            *(bf16x8*)&Bh[r][cc * 8] = *(const bf16x8*)(Bth + g);
            *(bf16x8*)&Bl[r][cc * 8] = *(const bf16x8*)(Btl + g);
        }
        __syncthreads();
        #pragma unroll
        for (int ks = 0; ks < 2; ++ks) {
            bf16x8 ah[4], al[4], bh[2], bl[2];
            #pragma unroll
            for (int i = 0; i < 4; ++i) {
                ah[i] = *(const bf16x8*)&Ah[wm * 64 + i * 16 + lid][ks * 32 + quad * 8];
                al[i] = *(const bf16x8*)&Al[wm * 64 + i * 16 + lid][ks * 32 + quad * 8];
            }
            #pragma unroll
            for (int j = 0; j < 2; ++j) {
                bh[j] = *(const bf16x8*)&Bh[wn * 32 + j * 16 + lid][ks * 32 + quad * 8];
                bl[j] = *(const bf16x8*)&Bl[wn * 32 + j * 16 + lid][ks * 32 + quad * 8];
            }
            #pragma unroll
            for (int i = 0; i < 4; ++i)
                #pragma unroll
                for (int j = 0; j < 2; ++j) {
                    f32x4 t = __builtin_amdgcn_mfma_f32_16x16x32_bf16(al[i], bh[j], acc[i][j], 0, 0, 0);
                    t = __builtin_amdgcn_mfma_f32_16x16x32_bf16(ah[i], bl[j], t, 0, 0, 0);
                    acc[i][j] = __builtin_amdgcn_mfma_f32_16x16x32_bf16(ah[i], bh[j], t, 0, 0, 0);
                }
        }
    }

    float bcol[2];
    #pragma unroll
    for (int j = 0; j < 2; ++j) bcol[j] = bias[col0 + wn * 32 + j * 16 + lid];
    #pragma unroll
    for (int i = 0; i < 4; ++i)
        #pragma unroll
        for (int j = 0; j < 2; ++j) {
            int colg = col0 + wn * 32 + j * 16 + lid;
            #pragma unroll
            for (int r = 0; r < 4; ++r) {
                int rowg = row0 + wm * 64 + i * 16 + quad * 4 + r;
                C[(size_t)rowg * 512 + colg] = acc[i][j][r] + bcol[j];
            }
        }
}

// ---------------------------------------------------------------------------
// V transpose through LDS: Vb[b,l,h,d] bf16 -> VtG[b,h,d,l] bf16 (coalesced)
// ---------------------------------------------------------------------------
__global__ __launch_bounds__(256) void vtrans_kernel(
    const __bf16* __restrict__ Vb, __bf16* __restrict__ VtG)
{
    __shared__ __bf16 t[64][72];
    const int tid = threadIdx.x;
    const int lt = blockIdx.x & 15, h = (blockIdx.x >> 4) & 7, b = blockIdx.x >> 7;
    const int rr = tid >> 3, cc = tid & 7;
    #pragma unroll
    for (int p = 0; p < 2; ++p) {
        int r = p * 32 + rr;      // l within tile
        *(bf16x8*)&t[r][cc * 8] =
            *(const bf16x8*)(Vb + (size_t)(b * LLEN + lt * 64 + r) * DDIM + h * 64 + cc * 8);
    }
    __syncthreads();
    #pragma unroll
    for (int p = 0; p < 2; ++p) {
        int d = p * 32 + rr;
        bf16x8 o;
        #pragma unroll
        for (int m = 0; m < 8; ++m) o[m] = t[cc * 8 + m][d];
        *(bf16x8*)(VtG + ((size_t)((b * 8 + h) * 64 + d)) * LLEN + lt * 64 + cc * 8) = o;
    }
}

// ---------------------------------------------------------------------------
// FiLM latent
// ---------------------------------------------------------------------------
__global__ __launch_bounds__(256) void film_latent_kernel(
    const float* __restrict__ latent, const float* __restrict__ Ws1,
    const float* __restrict__ bs1, float* __restrict__ film)
{
    __shared__ float sl[DLAT];
    const int b = blockIdx.x;
    const int tid = threadIdx.x;
    #pragma unroll
    for (int l = 0; l < 2; ++l) {
        int k = tid + l * 256;
        float x = latent[b * DLAT + k];
        sl[k] = x / (1.f + __expf(-x));
    }
    __syncthreads();
    int n = blockIdx.y * 256 + tid;
    float acc = bs1[n];
    for (int k = 0; k < DLAT; ++k)
        acc += sl[k] * Ws1[(size_t)k * 1024 + n];
    film[b * 1024 + n] = acc;
}

// ---------------------------------------------------------------------------
// MFMA attention (unchanged math; epilogue now emits O as hi/lo bf16 pair
// so the FC GEMM can run split-bf16 at near-fp32 accuracy)
// ---------------------------------------------------------------------------
__global__ __launch_bounds__(256) void attn_mfma_kernel(
    const __bf16* __restrict__ Qb, const __bf16* __restrict__ Kb,
    const __bf16* __restrict__ VtG, float* __restrict__ attn_out,
    __bf16* __restrict__ Ohi, __bf16* __restrict__ Olo)
{
    const int bid = blockIdx.x;
    const int qt = bid & 15;
    const int h  = (bid >> 4) & 7;
    const int b  = bid >> 7;
    const int q0 = qt * 64;
    const int tid = threadIdx.x;
    const int w    = tid >> 6;
    const int lane = tid & 63;
    const int quad = lane >> 4;
    const int lid  = lane & 15;

    __shared__ __bf16 KtS[64][72];
    __shared__ __bf16 VtS[64][72];
    __shared__ __bf16 PtS[4][16][72];

    const int myq = q0 + w * 16 + lid;
    const __bf16* qptr = Qb + (size_t)(b * LLEN + myq) * DDIM + h * 64 + quad * 8;
    const bf16x8 qf0 = *(const bf16x8*)(qptr);
    const bf16x8 qf1 = *(const bf16x8*)(qptr + 32);

    const size_t kbase = (size_t)(b * LLEN) * DDIM + h * 64;
    const size_t vbase = (size_t)((b * 8 + h) * 64) * LLEN;
    const f32x4 zero = {0.f, 0.f, 0.f, 0.f};
    const float C0 = 0.125f;

    // ---------------- pass 1: row sums ----------------
    float rsum = 0.f;
    for (int kt = 0; kt < 16; ++kt) {
        __syncthreads();
        #pragma unroll
        for (int rep = 0; rep < 2; ++rep) {
            int s = tid + rep * 256;
            int r = s >> 3, c = s & 7;
            *(bf16x8*)&KtS[r][c * 8] =
                *(const bf16x8*)(Kb + kbase + (size_t)(kt * 64 + r) * DDIM + c * 8);
        }
        __syncthreads();
        #pragma unroll
        for (int st = 0; st < 4; ++st) {
            bf16x8 a0 = *(const bf16x8*)&KtS[st * 16 + lid][quad * 8];
            bf16x8 a1 = *(const bf16x8*)&KtS[st * 16 + lid][32 + quad * 8];
            f32x4 c = __builtin_amdgcn_mfma_f32_16x16x32_bf16(a0, qf0, zero, 0, 0, 0);
            c = __builtin_amdgcn_mfma_f32_16x16x32_bf16(a1, qf1, c, 0, 0, 0);
            #pragma unroll
            for (int r = 0; r < 4; ++r) rsum += __expf(C0 * c[r]);
        }
    }
    rsum += __shfl_xor(rsum, 16, 64);
    rsum += __shfl_xor(rsum, 32, 64);
    const float rinv = 1.f / rsum;

    // ---------------- pass 2: attn write + PV ----------------
    f32x4 oacc[4] = {zero, zero, zero, zero};
    const size_t abase = ((size_t)((b * 8 + h) * LLEN + myq)) * LLEN;

    for (int kt = 0; kt < 16; ++kt) {
        __syncthreads();
        #pragma unroll
        for (int rep = 0; rep < 2; ++rep) {
            int s = tid + rep * 256;
            int r = s >> 3, c = s & 7;
            *(bf16x8*)&KtS[r][c * 8] =
                *(const bf16x8*)(Kb + kbase + (size_t)(kt * 64 + r) * DDIM + c * 8);
            *(bf16x8*)&VtS[r][c * 8] =
                *(const bf16x8*)(VtG + vbase + (size_t)r * LLEN + kt * 64 + c * 8);
        }
        __syncthreads();
        #pragma unroll
        for (int st = 0; st < 4; ++st) {
            bf16x8 a0 = *(const bf16x8*)&KtS[st * 16 + lid][quad * 8];
            bf16x8 a1 = *(const bf16x8*)&KtS[st * 16 + lid][32 + quad * 8];
            f32x4 c = __builtin_amdgcn_mfma_f32_16x16x32_bf16(a0, qf0, zero, 0, 0, 0);
            c = __builtin_amdgcn_mfma_f32_16x16x32_bf16(a1, qf1, c, 0, 0, 0);
            f32x4 p;
            bf16x4 pk;
            #pragma unroll
            for (int r = 0; r < 4; ++r) {
                p[r] = __expf(C0 * c[r]) * rinv;
                pk[r] = f2bf(p[r]);
            }
            *(f32x4*)(attn_out + abase + kt * 64 + st * 16 + quad * 4) = p;
            *(bf16x4*)&PtS[w][lid][st * 16 + quad * 4] = pk;
        }
        __syncthreads();
        #pragma unroll
        for (int kc = 0; kc < 2; ++kc) {
            bf16x8 pa = *(const bf16x8*)&PtS[w][lid][kc * 32 + quad * 8];
            #pragma unroll
            for (int nt = 0; nt < 4; ++nt) {
                bf16x8 vb = *(const bf16x8*)&VtS[nt * 16 + lid][kc * 32 + quad * 8];
                oacc[nt] = __builtin_amdgcn_mfma_f32_16x16x32_bf16(pa, vb, oacc[nt], 0, 0, 0);
            }
        }
    }

    // O epilogue: hi/lo bf16 split
    #pragma unroll
    for (int nt = 0; nt < 4; ++nt)
        #pragma unroll
        for (int r = 0; r < 4; ++r) {
            float val = oacc[nt][r];
            __bf16 hi = f2bf(val);
            size_t idx = (size_t)(b * LLEN + q0 + w * 16 + quad * 4 + r) * DDIM + h * 64 + nt * 16 + lid;
            Ohi[idx] = hi;
            Olo[idx] = f2bf(val - (float)hi);
        }
}

// ---------------------------------------------------------------------------
__device__ inline void block_reduce2(float& a, float& b) {
    #pragma unroll
    for (int off = 32; off > 0; off >>= 1) {
        a += __shfl_down(a, off, 64);
        b += __shfl_down(b, off, 64);
    }
    __shared__ float wa[4], wb[4];
    int lane = threadIdx.x & 63, w = threadIdx.x >> 6;
    if (lane == 0) { wa[w] = a; wb[w] = b; }
    __syncthreads();
    if (threadIdx.x == 0) {
        wa[0] = wa[0] + wa[1] + wa[2] + wa[3];
        wb[0] = wb[0] + wb[1] + wb[2] + wb[3];
    }
    __syncthreads();
    a = wa[0];
    b = wb[0];
}

__global__ __launch_bounds__(256) void film_ln_kernel(
    const float* __restrict__ X, const float* __restrict__ en_g,
    const float* __restrict__ en_b, const float* __restrict__ film,
    __bf16* __restrict__ HShi, __bf16* __restrict__ HSlo)
{
    const int row = blockIdx.x;
    const int b = row >> 10;
    const int tid = threadIdx.x;
    const size_t base = (size_t)row * DDIM;

    float x0 = X[base + tid];
    float x1 = X[base + 256 + tid];
    float s = x0 + x1;
    float s2 = x0 * x0 + x1 * x1;
    block_reduce2(s, s2);
    float mean = s * (1.f / 512.f);
    float var = s2 * (1.f / 512.f) - mean * mean;
    float inv = rsqrtf(var + 1e-5f);

    #pragma unroll
    for (int l = 0; l < 2; ++l) {
        int d = tid + l * 256;
        float x = (l == 0) ? x0 : x1;
        float nh = (x - mean) * inv * en_g[d] + en_b[d];
        float sc = film[b * 1024 + d];
        float sh = film[b * 1024 + 512 + d];
        float hv = nh * (1.f + sc) + sh;
        float sv = hv / (1.f + __expf(-hv));
        __bf16 hi = f2bf(sv);
        HShi[base + d] = hi;
        HSlo[base + d] = f2bf(sv - (float)hi);
    }
}

__global__ __launch_bounds__(256) void final_ln_kernel(
    const float* __restrict__ H2, const float* __restrict__ resid,
    const float* __restrict__ g, const float* __restrict__ bta,
    float* __restrict__ out)
{
    const int row = blockIdx.x;
    const int tid = threadIdx.x;
    const size_t base = (size_t)row * DDIM;

    float x0 = H2[base + tid] + resid[base + tid];
    float x1 = H2[base + 256 + tid] + resid[base + 256 + tid];
    float s = x0 + x1;
    float s2 = x0 * x0 + x1 * x1;
    block_reduce2(s, s2);
    float mean = s * (1.f / 512.f);
    float var = s2 * (1.f / 512.f) - mean * mean;
    float inv = rsqrtf(var + 1e-6f);

    #pragma unroll
    for (int l = 0; l < 2; ++l) {
        int d = tid + l * 256;
        float x = (l == 0) ? x0 : x1;
        out[base + d] = (x - mean) * inv * g[d] + bta[d];
    }
}

// ---------------------------------------------------------------------------
extern "C" void kernel_launch(void* const* d_in, const int* in_sizes, int n_in,
                              void* d_out, int out_size, void* d_ws, size_t ws_size,
                              hipStream_t stream)
{
    const float* q      = (const float*)d_in[0];
    const float* k      = (const float*)d_in[1];
    const float* v      = (const float*)d_in[2];
    const float* latent = (const float*)d_in[3];
    const float* Wq  = (const float*)d_in[4];
    const float* bq  = (const float*)d_in[5];
    const float* Wk  = (const float*)d_in[6];
    const float* bk  = (const float*)d_in[7];
    const float* Wv  = (const float*)d_in[8];
    const float* bv  = (const float*)d_in[9];
    const float* Wfc = (const float*)d_in[10];
    const float* bfc = (const float*)d_in[11];
    const float* Ws1 = (const float*)d_in[12];
    const float* bs1 = (const float*)d_in[13];
    const float* Ws2 = (const float*)d_in[14];
    const float* bs2 = (const float*)d_in[15];
    const float* en_g = (const float*)d_in[16];
    const float* en_b = (const float*)d_in[17];
    const float* ln_g = (const float*)d_in[18];
    const float* ln_b = (const float*)d_in[19];

    float* out  = (float*)d_out;            // [8192, 512]
    float* attn = out + ROWELEM;            // [8, 8, 1024, 1024]

    char* ws = (char*)d_ws;
    __bf16* Qb   = (__bf16*)(ws + 0);              // 8.4 MB
    __bf16* Kb   = (__bf16*)(ws + 8388608);
    __bf16* Vb   = (__bf16*)(ws + 16777216);
    __bf16* VtG  = (__bf16*)(ws + 25165824);
    __bf16* Ohi  = (__bf16*)(ws + 33554432);
    __bf16* Olo  = (__bf16*)(ws + 41943040);
    __bf16* WqT  = (__bf16*)(ws + 50331648);       // 512 KB each
    __bf16* WkT  = (__bf16*)(ws + 50855936);
    __bf16* WvT  = (__bf16*)(ws + 51380224);
    __bf16* WfhT = (__bf16*)(ws + 51904512);
    __bf16* WflT = (__bf16*)(ws + 52428800);
    __bf16* W2hT = (__bf16*)(ws + 52953088);
    __bf16* W2lT = (__bf16*)(ws + 53477376);
    float*  film = (float*)(ws + 54001664);        // 32 KB

    // aliases over dead regions:
    float*  F1   = (float*)(ws + 0);               // over Qb+Kb (dead after attn)
    __bf16* HShi = Ohi;                            // O dead after FC gemm
    __bf16* HSlo = Olo;
    float*  H2   = (float*)(ws + 16777216);        // over Vb+VtG (dead after attn)

    // weight prep (tiny)
    wtrans_kernel<<<64, 256, 0, stream>>>(Wq, WqT);
    wtrans_kernel<<<64, 256, 0, stream>>>(Wk, WkT);
    wtrans_kernel<<<64, 256, 0, stream>>>(Wv, WvT);
    wtrans_hilo_kernel<<<64, 256, 0, stream>>>(Wfc, WfhT, WflT);
    wtrans_hilo_kernel<<<64, 256, 0, stream>>>(Ws2, W2hT, W2lT);
    film_latent_kernel<<<dim3(BB, 4), 256, 0, stream>>>(latent, Ws1, bs1, film);

    dim3 ggrid(8, 64);   // N/64 x M/128
    gemm_qkv_mfma<<<ggrid, 256, 0, stream>>>(q, WqT, bq, Qb);
    gemm_qkv_mfma<<<ggrid, 256, 0, stream>>>(k, WkT, bk, Kb);
    gemm_qkv_mfma<<<ggrid, 256, 0, stream>>>(v, WvT, bv, Vb);
    vtrans_kernel<<<1024, 256, 0, stream>>>(Vb, VtG);

    attn_mfma_kernel<<<1024, 256, 0, stream>>>(Qb, Kb, VtG, attn, Ohi, Olo);

    gemm_split_mfma<<<ggrid, 256, 0, stream>>>(Ohi, Olo, WfhT, WflT, bfc, F1);
    film_ln_kernel<<<NROW, 256, 0, stream>>>(F1, en_g, en_b, film, HShi, HSlo);
    gemm_split_mfma<<<ggrid, 256, 0, stream>>>(HShi, HSlo, W2hT, W2lT, bs2, H2);
    final_ln_kernel<<<NROW, 256, 0, stream>>>(H2, q, ln_g, ln_b, out);
}